// Round 11
// baseline (273.912 us; speedup 1.0000x reference)
//
#include <hip/hip_runtime.h>

#define HW (512 * 512)
#define QP 260   // pitch (floats): >=256, %32==4 -> staggered banks for row-strided reads
#define WCH 384  // W chunks per head: 2 planes x 24 rows x 8 slots (16 B each)

typedef __bf16 bf16;
typedef __attribute__((ext_vector_type(8))) __bf16 bf16x8;
typedef __attribute__((ext_vector_type(4))) float f32x4;

__device__ __forceinline__ void cvt_split(float f, bf16& h, bf16& l) {
    h = (bf16)f;
    l = (bf16)(f - (float)h);
}

// W -> fragment-ordered bf16 hi/lo chunks in d_ws (48 KB, L2-resident).
// layout: o = ((head*2+plane)*24 + r)*64 + s*8 + j  maps to  w[grow(r,head)][s*8+j],
// grow = (r>>3)*64 + head*8 + (r&7)  (r = local qkv row 0..23, s = 16B k-slot).
__global__ __launch_bounds__(256) void wcvt_kernel(
    const float* __restrict__ w, bf16* __restrict__ wf)
{
    const int o = blockIdx.x * 256 + threadIdx.x;
    if (o >= 8 * WCH * 8) return;
    const int j  = o & 7;
    const int s  = (o >> 3) & 7;
    const int rc = o >> 6;
    const int r  = rc % 24;
    const int hp = rc / 24;
    const int pl = hp & 1;
    const int h  = hp >> 1;
    const int grow = (r >> 3) * 64 + h * 8 + (r & 7);
    bf16 hi, lo;
    cvt_split(w[grow * 64 + s * 8 + j], hi, lo);
    wf[o] = pl ? lo : hi;
}

// Two windows per block (R10, verified). NEW: W slice for head h+1 is prefetched
// (issue global loads at head-h top, ds_write after phase B, read after S3) into a
// parity-buffered 12 KB LDS tile, taking the W global-load latency OUT of the
// S3->S4 critical slot. Slots XOR-swizzled (s^(r&7)) so B-frag ds_read_b128 by
// (c16,q4) lanes spreads over 8 slot-banks (2-way = free).
// No launch-bounds cap below natural demand (R4/R5/R9: caps => spill traffic).
__global__ __launch_bounds__(256, 2) void lwmsa_kernel(
    const float* __restrict__ x,
    const bf16* __restrict__ wf,
    float* __restrict__ out)
{
    const int blk  = blockIdx.x;       // 0..2047
    const int b    = blk >> 9;
    const int wrow = (blk >> 4) & 31;
    const int wp   = blk & 15;         // col pair: wcol = 2*wp + w
    const int n    = threadIdx.x;      // 0..255 = pixel in window
    const int lane = n & 63;
    const int wvid = n >> 6;           // wave 0..3
    const int c16  = lane & 15;
    const int q4   = lane >> 4;

    __shared__ float qk[2][24 * QP];   // per window: q rows 0-7, k 8-15, v 16-23
    __shared__ float kvp[2][4 * 64];
    __shared__ float kv_s[2][64];
    __shared__ float tp[2][2][4];      // [win][parity][wave]
    __shared__ bf16  wlds[2 * 3072];   // [parity][plane 1536 each], swizzled slots

    int base[2], xwin[2];
    #pragma unroll
    for (int w = 0; w < 2; ++w) {
        const int wcol = wp * 2 + w;
        base[w] = b * (64 * HW) + (wrow * 16 + (n >> 4)) * 512 + wcol * 16 + (n & 15);
        xwin[w] = b * (64 * HW) + (wrow * 16) * 512 + wcol * 16;
    }

    // swizzled LDS dest offsets for this thread's W chunks (head-independent)
    auto chunk_dst = [](int c) {
        const int pl = c / 192;
        const int cc = c % 192;
        const int r  = cc >> 3;
        const int s  = cc & 7;
        return pl * 1536 + (r * 8 + (s ^ (r & 7))) * 8;
    };
    const int dst0 = chunk_dst(n);
    const int dst1 = (n < 128) ? chunk_dst(n + 256) : 0;

    // ---- A-fragments (X) for both windows, hi/lo, global -> registers ----
    bf16x8 ah[2][2][4], al[2][2][4];   // [win][ks][mt]
    #pragma unroll
    for (int w = 0; w < 2; ++w)
        #pragma unroll
        for (int ks = 0; ks < 2; ++ks)
            #pragma unroll
            for (int mt = 0; mt < 4; ++mt) {
                const int row = wvid * 4 + mt;
                const float* xp = x + xwin[w] + row * 512 + c16 + (ks * 32 + q4 * 8) * HW;
                #pragma unroll
                for (int j = 0; j < 8; ++j) {
                    bf16 h, l;
                    cvt_split(xp[j * HW], h, l);
                    ah[w][ks][mt][j] = h;
                    al[w][ks][mt][j] = l;
                }
            }

    // ---- per-head MFMA + stage; B-frags from LDS W tile (parity-buffered) ----
    auto mfma_stage = [&](const bf16x8 (&Ah)[2][4], const bf16x8 (&Al)[2][4],
                          float* __restrict__ qkb, int par) {
        f32x4 acc[4][2];
        #pragma unroll
        for (int mt = 0; mt < 4; ++mt)
            #pragma unroll
            for (int nt = 0; nt < 2; ++nt)
                acc[mt][nt] = (f32x4){0.f, 0.f, 0.f, 0.f};

        const bf16* wb = &wlds[par * 3072];
        #pragma unroll
        for (int ks = 0; ks < 2; ++ks) {
            #pragma unroll
            for (int nt = 0; nt < 2; ++nt) {
                const int ml   = nt * 16 + c16;                 // 0..31; valid < 24
                const int ml8  = (ml < 24) ? ml : 0;            // pad rows read row 0
                const int slot = (ks * 4 + q4) ^ (ml8 & 7);
                const bf16x8 bh = *(const bf16x8*)&wb[(ml8 * 8 + slot) * 8];
                const bf16x8 bl = *(const bf16x8*)&wb[1536 + (ml8 * 8 + slot) * 8];
                #pragma unroll
                for (int mt = 0; mt < 4; ++mt) {
                    acc[mt][nt] = __builtin_amdgcn_mfma_f32_16x16x32_bf16(Ah[ks][mt], bh, acc[mt][nt], 0, 0, 0);
                    acc[mt][nt] = __builtin_amdgcn_mfma_f32_16x16x32_bf16(Al[ks][mt], bh, acc[mt][nt], 0, 0, 0);
                    acc[mt][nt] = __builtin_amdgcn_mfma_f32_16x16x32_bf16(Ah[ks][mt], bl, acc[mt][nt], 0, 0, 0);
                }
            }
        }

        // D: lane holds qkv-row ml=nt*16+c16 at px=(wvid*4+mt)*16+q4*4+reg
        #pragma unroll
        for (int nt = 0; nt < 2; ++nt) {
            const int ml = nt * 16 + c16;
            if (ml < 24) {
                #pragma unroll
                for (int mt = 0; mt < 4; ++mt) {
                    const int px = (wvid * 4 + mt) * 16 + q4 * 4;
                    *(float4*)&qkb[ml * QP + px] = *(float4*)&acc[mt][nt];
                }
            }
        }
    };

    float feat[2][8];
    #pragma unroll
    for (int w = 0; w < 2; ++w)
        #pragma unroll
        for (int d = 0; d < 8; ++d) feat[w][d] = 0.f;

    // ---- init: stage head-0 W into parity 0, then head-0 projections ----
    {
        const float4* wsrc = (const float4*)wf;      // head 0 chunks
        const float4 c0 = wsrc[n];
        *(float4*)&wlds[dst0] = c0;
        if (n < 128) {
            const float4 c1 = wsrc[n + 256];
            *(float4*)&wlds[dst1] = c1;
        }
    }
    __syncthreads();  // W(0) visible
    mfma_stage(ah[0], al[0], qk[0], 0);
    mfma_stage(ah[1], al[1], qk[1], 0);
    __syncthreads();  // S_init: head-0 projections visible

    for (int h = 0; h < 8; ++h) {
        // ---- prefetch ISSUE: W chunks for head h+1 (consumed after S3) ----
        float4 pc0, pc1;
        if (h < 7) {
            const float4* wsrc = (const float4*)(wf + (h + 1) * (WCH * 8));
            pc0 = wsrc[n];
            if (n < 128) pc1 = wsrc[n + 256];
        }

        // ---- phase A (x2): proj+feat, elu1, row sums; write kf/av back ----
        float qf[2][8], Sq[2], tpart[2];
        #pragma unroll
        for (int w = 0; w < 2; ++w) {
            Sq[w] = 0.f; tpart[w] = 0.f;
            #pragma unroll
            for (int d = 0; d < 8; ++d) {
                const float aq = qk[w][d * QP + n]        + feat[w][d];
                const float ak = qk[w][(8 + d) * QP + n]  + feat[w][d];
                const float av = qk[w][(16 + d) * QP + n] + feat[w][d];
                qf[w][d] = aq > 0.f ? aq + 1.f : __expf(aq);
                const float kf = ak > 0.f ? ak + 1.f : __expf(ak);
                Sq[w]    += qf[w][d];
                tpart[w] += kf;
                qk[w][(8 + d) * QP + n]  = kf;
                qk[w][(16 + d) * QP + n] = av;
            }
        }

        #pragma unroll
        for (int off = 1; off < 64; off <<= 1) {
            tpart[0] += __shfl_xor(tpart[0], off, 64);
            tpart[1] += __shfl_xor(tpart[1], off, 64);
        }
        if (lane == 0) {
            tp[0][h & 1][wvid] = tpart[0];
            tp[1][h & 1][wvid] = tpart[1];
        }

        // wave-internal handoff: phase B reads only this wave's 64 columns (R8-verified)
        asm volatile("s_waitcnt lgkmcnt(0)" ::: "memory");

        // ---- phase B (x2): kv partials over this wave's 64 px ----
        #pragma unroll
        for (int w = 0; w < 2; ++w) {
            const float4* kr = (const float4*)(qk[w] + (8 + (lane >> 3)) * QP + wvid * 64);
            const float4* vr = (const float4*)(qk[w] + (16 + (lane & 7)) * QP + wvid * 64);
            float s0 = 0.f, s1 = 0.f, s2 = 0.f, s3 = 0.f;
            #pragma unroll
            for (int j = 0; j < 16; ++j) {
                const float4 kk = kr[j];
                const float4 vv = vr[j];
                s0 = fmaf(kk.x, vv.x, s0);
                s1 = fmaf(kk.y, vv.y, s1);
                s2 = fmaf(kk.z, vv.z, s2);
                s3 = fmaf(kk.w, vv.w, s3);
            }
            kvp[w][wvid * 64 + lane] = (s0 + s1) + (s2 + s3);
        }

        // ---- prefetch WRITE: park W(h+1) in the idle parity tile ----
        if (h < 7) {
            const int par = (h + 1) & 1;
            *(float4*)&wlds[par * 3072 + dst0] = pc0;
            if (n < 128) *(float4*)&wlds[par * 3072 + dst1] = pc1;
        }

        __syncthreads();  // S3: kvp + tp + W(h+1) visible; qk buffers dead -> restage

        // ---- phase C: final kv reduce overlapped with next head's MFMA ----
        if (n < 64) {
            kv_s[0][n] = (kvp[0][n] + kvp[0][64 + n]) + (kvp[0][128 + n] + kvp[0][192 + n]);
        } else if (n < 128) {
            const int m = n - 64;
            kv_s[1][m] = (kvp[1][m] + kvp[1][64 + m]) + (kvp[1][128 + m] + kvp[1][192 + m]);
        }

        if (h < 7) {
            const int par = (h + 1) & 1;
            mfma_stage(ah[0], al[0], qk[0], par);
            mfma_stage(ah[1], al[1], qk[1], par);
        }

        __syncthreads();  // S4: kv_s + next head's projections visible

        // ---- phase D (x2): z, feat, out ----
        #pragma unroll
        for (int w = 0; w < 2; ++w) {
            const float T  = ((tp[w][h & 1][0] + tp[w][h & 1][1]) +
                              (tp[w][h & 1][2] + tp[w][h & 1][3])) + 8.0f * 1e-6f;
            const float zi = 1.0f / (Sq[w] * T);

            float ft[8];
            #pragma unroll
            for (int d = 0; d < 8; ++d) ft[d] = 0.f;
            #pragma unroll
            for (int d = 0; d < 8; ++d) {
                const float qd = qf[w][d];
                const float4 a  = ((const float4*)(kv_s[w] + d * 8))[0];
                const float4 bb = ((const float4*)(kv_s[w] + d * 8))[1];
                ft[0] = fmaf(qd, a.x,  ft[0]);
                ft[1] = fmaf(qd, a.y,  ft[1]);
                ft[2] = fmaf(qd, a.z,  ft[2]);
                ft[3] = fmaf(qd, a.w,  ft[3]);
                ft[4] = fmaf(qd, bb.x, ft[4]);
                ft[5] = fmaf(qd, bb.y, ft[5]);
                ft[6] = fmaf(qd, bb.z, ft[6]);
                ft[7] = fmaf(qd, bb.w, ft[7]);
            }
            #pragma unroll
            for (int d = 0; d < 8; ++d) {
                feat[w][d] = ft[d] * zi;
                out[base[w] + (h * 8 + d) * HW] = feat[w][d];
            }
        }
    }
}

extern "C" void kernel_launch(void* const* d_in, const int* in_sizes, int n_in,
                              void* d_out, int out_size, void* d_ws, size_t ws_size,
                              hipStream_t stream) {
    const float* x  = (const float*)d_in[0];
    const float* w  = (const float*)d_in[1];
    float* out      = (float*)d_out;
    bf16* wf = (bf16*)d_ws;   // 8 heads * 384 chunks * 16 B = 48 KB
    wcvt_kernel<<<dim3(96), dim3(256), 0, stream>>>(w, wf);
    lwmsa_kernel<<<dim3(2048), dim3(256), 0, stream>>>(x, wf, out);
}